// Round 1
// baseline (1091.419 us; speedup 1.0000x reference)
//
#include <hip/hip_runtime.h>
#include <math.h>

#define T_DIM 1024
#define B_DIM 16
#define C_DIM 1024
#define H_DIM 16
#define K_TAPS 7
#define PAD_LEFT 3
#define OUT_DIM 1024
#define M_DIM (T_DIM * B_DIM)   // 16384

// ---------------------------------------------------------------------------
// Generic tiled fp32 GEMM with bias:  C[M,N] = A[M,K] @ B[K,N] + bias[N]
// BM=128, BN=128, BK=16, 256 threads, 8x8 microtile per thread.
// M, K assumed multiples of BM/BK (true here: M=16384, K=1024).
// N may be < BN (N=112 case) -> guarded loads/stores (N % 4 == 0 required).
// ---------------------------------------------------------------------------
template <int BM, int BN, int BK, int TM, int TN>
__global__ __launch_bounds__(256) void gemm_bias(const float* __restrict__ A,
                                                 const float* __restrict__ Bm,
                                                 const float* __restrict__ bias,
                                                 float* __restrict__ Cm,
                                                 int M, int N, int Kd) {
    __shared__ float As[BK][BM + 4];   // A stored transposed: As[k][m]
    __shared__ float Bs[BK][BN + 4];   // B stored as-is:     Bs[k][n]

    const int bm = blockIdx.y * BM;
    const int bn = blockIdx.x * BN;
    const int tid = threadIdx.x;
    const int ty = tid / (BN / TN);    // 0..15
    const int tx = tid % (BN / TN);    // 0..15

    float acc[TM][TN];
#pragma unroll
    for (int i = 0; i < TM; ++i)
#pragma unroll
        for (int j = 0; j < TN; ++j) acc[i][j] = 0.f;

    for (int k0 = 0; k0 < Kd; k0 += BK) {
        // --- stage A tile: BM x BK, float4 loads, transpose into LDS ---
#pragma unroll
        for (int l = 0; l < (BM * BK) / (256 * 4); ++l) {
            int idx = tid + l * 256;             // float4 index
            int row = idx / (BK / 4);
            int kq  = idx % (BK / 4);
            float4 v = *reinterpret_cast<const float4*>(
                &A[(size_t)(bm + row) * Kd + k0 + kq * 4]);
            As[kq * 4 + 0][row] = v.x;
            As[kq * 4 + 1][row] = v.y;
            As[kq * 4 + 2][row] = v.z;
            As[kq * 4 + 3][row] = v.w;
        }
        // --- stage B tile: BK x BN ---
#pragma unroll
        for (int l = 0; l < (BK * BN) / (256 * 4); ++l) {
            int idx = tid + l * 256;
            int kk  = idx / (BN / 4);
            int cq  = idx % (BN / 4);
            int col = bn + cq * 4;
            float4 v = make_float4(0.f, 0.f, 0.f, 0.f);
            if (col < N)
                v = *reinterpret_cast<const float4*>(
                    &Bm[(size_t)(k0 + kk) * N + col]);
            *reinterpret_cast<float4*>(&Bs[kk][cq * 4]) = v;
        }
        __syncthreads();

        // --- inner product over BK ---
#pragma unroll
        for (int kk = 0; kk < BK; ++kk) {
            float a[TM], b[TN];
            float4 a0 = *reinterpret_cast<float4*>(&As[kk][ty * TM]);
            float4 a1 = *reinterpret_cast<float4*>(&As[kk][ty * TM + 4]);
            float4 b0 = *reinterpret_cast<float4*>(&Bs[kk][tx * TN]);
            float4 b1 = *reinterpret_cast<float4*>(&Bs[kk][tx * TN + 4]);
            a[0]=a0.x; a[1]=a0.y; a[2]=a0.z; a[3]=a0.w;
            a[4]=a1.x; a[5]=a1.y; a[6]=a1.z; a[7]=a1.w;
            b[0]=b0.x; b[1]=b0.y; b[2]=b0.z; b[3]=b0.w;
            b[4]=b1.x; b[5]=b1.y; b[6]=b1.z; b[7]=b1.w;
#pragma unroll
            for (int i = 0; i < TM; ++i)
#pragma unroll
                for (int j = 0; j < TN; ++j)
                    acc[i][j] = fmaf(a[i], b[j], acc[i][j]);
        }
        __syncthreads();
    }

    // --- epilogue: add bias, store ---
#pragma unroll
    for (int i = 0; i < TM; ++i) {
        int row = bm + ty * TM + i;
#pragma unroll
        for (int j = 0; j < TN; j += 4) {
            int col = bn + tx * TN + j;
            if (col < N) {
                float4 v;
                v.x = acc[i][j + 0] + bias[col + 0];
                v.y = acc[i][j + 1] + bias[col + 1];
                v.z = acc[i][j + 2] + bias[col + 2];
                v.w = acc[i][j + 3] + bias[col + 3];
                *reinterpret_cast<float4*>(&Cm[(size_t)row * N + col]) = v;
            }
        }
    }
}

// ---------------------------------------------------------------------------
// Softmax over K=7 taps; one thread per (m, h) row of 7. In-place safe.
// ---------------------------------------------------------------------------
__global__ void softmax7(const float* __restrict__ q, float* __restrict__ w,
                         int rows) {
    int r = blockIdx.x * blockDim.x + threadIdx.x;
    if (r >= rows) return;
    const float* p = q + (size_t)r * K_TAPS;
    float mx = p[0];
#pragma unroll
    for (int k = 1; k < K_TAPS; ++k) mx = fmaxf(mx, p[k]);
    float e[K_TAPS], s = 0.f;
#pragma unroll
    for (int k = 0; k < K_TAPS; ++k) { e[k] = expf(p[k] - mx); s += e[k]; }
    float inv = 1.f / s;
    float* o = w + (size_t)r * K_TAPS;
#pragma unroll
    for (int k = 0; k < K_TAPS; ++k) o[k] = e[k] * inv;
}

// ---------------------------------------------------------------------------
// Dynamic conv along time: out[m,c] = sum_k h[(t+k-3)*B + b, c] * w[m, c/64, k]
//                                   + conv_bias[c]
// One block per m-row (1024 channels), 256 threads x float4.
// ---------------------------------------------------------------------------
__global__ __launch_bounds__(256) void dynconv(const float* __restrict__ h,
                                               const float* __restrict__ w,
                                               const float* __restrict__ cbias,
                                               float* __restrict__ out) {
    const int m = blockIdx.x;
    const int t = m >> 4;        // m / B_DIM
    const int b = m & 15;        // m % B_DIM

    __shared__ float ws[H_DIM * K_TAPS];
    if (threadIdx.x < H_DIM * K_TAPS)
        ws[threadIdx.x] = w[(size_t)m * H_DIM * K_TAPS + threadIdx.x];
    __syncthreads();

    const int c = threadIdx.x * 4;      // 0..1020
    const int hh = c >> 6;              // head index

    float4 bias = *reinterpret_cast<const float4*>(&cbias[c]);
    float acc0 = bias.x, acc1 = bias.y, acc2 = bias.z, acc3 = bias.w;

#pragma unroll
    for (int k = 0; k < K_TAPS; ++k) {
        int tt = t + k - PAD_LEFT;
        if (tt < 0 || tt >= T_DIM) continue;
        float4 hv = *reinterpret_cast<const float4*>(
            &h[((size_t)tt * B_DIM + b) * C_DIM + c]);
        float wk = ws[hh * K_TAPS + k];
        acc0 = fmaf(hv.x, wk, acc0);
        acc1 = fmaf(hv.y, wk, acc1);
        acc2 = fmaf(hv.z, wk, acc2);
        acc3 = fmaf(hv.w, wk, acc3);
    }
    float4 o = make_float4(acc0, acc1, acc2, acc3);
    *reinterpret_cast<float4*>(&out[(size_t)m * C_DIM + c]) = o;
}

// ---------------------------------------------------------------------------
extern "C" void kernel_launch(void* const* d_in, const int* in_sizes, int n_in,
                              void* d_out, int out_size, void* d_ws,
                              size_t ws_size, hipStream_t stream) {
    const float* x     = (const float*)d_in[0];
    const float* W1    = (const float*)d_in[1];
    const float* b1    = (const float*)d_in[2];
    const float* Wq    = (const float*)d_in[3];
    const float* bq    = (const float*)d_in[4];
    const float* cbias = (const float*)d_in[5];
    const float* W2    = (const float*)d_in[6];
    const float* b2    = (const float*)d_in[7];
    float* out = (float*)d_out;

    float* ws   = (float*)d_ws;
    float* h    = ws;                                  // 16384*1024 = 64 MB
    float* conv = ws + (size_t)M_DIM * C_DIM;          // 64 MB
    float* q    = ws + 2 * (size_t)M_DIM * C_DIM;      // 16384*112 = 7 MB

    dim3 blk(256);

    // 1) h = x @ W1 + b1       [16384 x 1024]
    gemm_bias<128, 128, 16, 8, 8>
        <<<dim3(C_DIM / 128, M_DIM / 128), blk, 0, stream>>>(
            x, W1, b1, h, M_DIM, C_DIM, C_DIM);

    // 2) q = h @ Wq + bq       [16384 x 112]
    gemm_bias<128, 128, 16, 8, 8>
        <<<dim3(1, M_DIM / 128), blk, 0, stream>>>(
            h, Wq, bq, q, M_DIM, H_DIM * K_TAPS, C_DIM);

    // 3) w = softmax_K(q)      in-place
    softmax7<<<dim3((M_DIM * H_DIM + 255) / 256), blk, 0, stream>>>(
        q, q, M_DIM * H_DIM);

    // 4) conv = dynamic_conv(h, w) + conv_bias   [16384 x 1024]
    dynconv<<<dim3(M_DIM), blk, 0, stream>>>(h, q, cbias, conv);

    // 5) out = conv @ W2 + b2  [16384 x 1024]
    gemm_bias<128, 128, 16, 8, 8>
        <<<dim3(OUT_DIM / 128, M_DIM / 128), blk, 0, stream>>>(
            conv, W2, b2, out, M_DIM, OUT_DIM, C_DIM);
}

// Round 2
// 207.754 us; speedup vs baseline: 5.2534x; 5.2534x over previous
//
#include <hip/hip_runtime.h>
#include <math.h>

#define T_DIM 1024
#define B_DIM 16
#define C_DIM 1024
#define H_DIM 16
#define K_TAPS 7
#define PAD_LEFT 3
#define OUT_DIM 1024
#define M_DIM (T_DIM * B_DIM)   // 16384
#define HK 112                  // H_DIM * K_TAPS
#define HKP 128                 // padded to tile width

typedef __attribute__((ext_vector_type(8))) short bf16x8;  // 8 bf16 = 4 VGPRs
typedef __attribute__((ext_vector_type(4))) float f32x4;

__device__ __forceinline__ ushort f2bf(float f) {
    union { float f; unsigned u; } v; v.f = f;
    unsigned u = v.u;
    u += 0x7fffu + ((u >> 16) & 1u);   // round-nearest-even
    return (ushort)(u >> 16);
}
__device__ __forceinline__ float bf2f(ushort h) {
    union { unsigned u; float f; } v; v.u = ((unsigned)h) << 16;
    return v.f;
}

// ---------------------------------------------------------------------------
// fp32 -> bf16 convert, 8 elems/thread, 16B stores
// ---------------------------------------------------------------------------
__global__ __launch_bounds__(256) void cvt_bf16x8(const float* __restrict__ in,
                                                  ushort* __restrict__ out,
                                                  int n8) {
    int i = blockIdx.x * blockDim.x + threadIdx.x;
    if (i >= n8) return;
    const float4* p = (const float4*)in;
    float4 a = p[2 * i], b = p[2 * i + 1];
    uint4 o;
    o.x = (unsigned)f2bf(a.x) | ((unsigned)f2bf(a.y) << 16);
    o.y = (unsigned)f2bf(a.z) | ((unsigned)f2bf(a.w) << 16);
    o.z = (unsigned)f2bf(b.x) | ((unsigned)f2bf(b.y) << 16);
    o.w = (unsigned)f2bf(b.z) | ((unsigned)f2bf(b.w) << 16);
    ((uint4*)out)[i] = o;
}

// ---------------------------------------------------------------------------
// Transpose + convert: Wt[n][k] (bf16) = W[k][n] (fp32). n >= N -> 0 pad.
// grid: (Npad/32, K/32), block (32, 8)
// ---------------------------------------------------------------------------
__global__ void transpose_cvt(const float* __restrict__ W,
                              ushort* __restrict__ Wt,
                              int Kd, int N, int Npad) {
    __shared__ float tile[32][33];
    int n0 = blockIdx.x * 32, k0 = blockIdx.y * 32;
    int tx = threadIdx.x, ty = threadIdx.y;
#pragma unroll
    for (int j = 0; j < 4; ++j) {
        int k = k0 + ty * 4 + j;
        int n = n0 + tx;
        tile[ty * 4 + j][tx] = (n < N) ? W[(size_t)k * N + n] : 0.f;
    }
    __syncthreads();
#pragma unroll
    for (int j = 0; j < 4; ++j) {
        int n = n0 + ty * 4 + j;
        if (n < Npad)
            Wt[(size_t)n * Kd + k0 + tx] = f2bf(tile[tx][ty * 4 + j]);
    }
}

// ---------------------------------------------------------------------------
// bf16 MFMA GEMM (m97 structure): C[M,N] = A[M,K] @ Bt[N,K]^T + bias
// 128x128 tile, BK=32, 256 threads (4 waves, 2x2), 4x4 16x16x32 frags/wave.
// A, Bt bf16; C fp32 or bf16. NGUARD for N < 128*gridDim.x (N%16-free cols).
// ---------------------------------------------------------------------------
template <bool OUT_BF16, bool NGUARD>
__global__ __launch_bounds__(256) void gemm_mfma(const ushort* __restrict__ A,
                                                 const ushort* __restrict__ Bt,
                                                 const float* __restrict__ bias,
                                                 void* __restrict__ Cp,
                                                 int Kd, int N, int ldc) {
    __shared__ ushort Als[128 * 32];
    __shared__ ushort Bls[128 * 32];
    const int tid  = threadIdx.x;
    const int lane = tid & 63;
    const int wid  = tid >> 6;
    const int wr = wid >> 1, wc = wid & 1;
    const int bm = blockIdx.y * 128, bn = blockIdx.x * 128;
    const int fq = lane >> 4, fr = lane & 15;

    f32x4 acc[4][4];
#pragma unroll
    for (int m = 0; m < 4; ++m)
#pragma unroll
        for (int n = 0; n < 4; ++n) acc[m][n] = (f32x4){0.f, 0.f, 0.f, 0.f};

    // staging chunk ids for this lane (16B chunks; 4 chunks per 64B row)
    const int c0 = wid * 128 + lane;
    const int c1 = c0 + 64;
    const int r0 = c0 >> 2, o0 = (c0 & 3) * 8;
    const int r1 = c1 >> 2, o1 = (c1 & 3) * 8;

    for (int k0 = 0; k0 < Kd; k0 += 32) {
        __builtin_amdgcn_global_load_lds(
            (const __attribute__((address_space(1))) void*)&A[(size_t)(bm + r0) * Kd + k0 + o0],
            (__attribute__((address_space(3))) void*)&Als[(wid * 2 + 0) * 512], 16, 0, 0);
        __builtin_amdgcn_global_load_lds(
            (const __attribute__((address_space(1))) void*)&A[(size_t)(bm + r1) * Kd + k0 + o1],
            (__attribute__((address_space(3))) void*)&Als[(wid * 2 + 1) * 512], 16, 0, 0);
        __builtin_amdgcn_global_load_lds(
            (const __attribute__((address_space(1))) void*)&Bt[(size_t)(bn + r0) * Kd + k0 + o0],
            (__attribute__((address_space(3))) void*)&Bls[(wid * 2 + 0) * 512], 16, 0, 0);
        __builtin_amdgcn_global_load_lds(
            (const __attribute__((address_space(1))) void*)&Bt[(size_t)(bn + r1) * Kd + k0 + o1],
            (__attribute__((address_space(3))) void*)&Bls[(wid * 2 + 1) * 512], 16, 0, 0);
        __syncthreads();

        bf16x8 af[4], bfr[4];
#pragma unroll
        for (int m = 0; m < 4; ++m)
            af[m] = *(const bf16x8*)&Als[(wr * 64 + m * 16 + fr) * 32 + fq * 8];
#pragma unroll
        for (int n = 0; n < 4; ++n)
            bfr[n] = *(const bf16x8*)&Bls[(wc * 64 + n * 16 + fr) * 32 + fq * 8];
#pragma unroll
        for (int m = 0; m < 4; ++m)
#pragma unroll
            for (int n = 0; n < 4; ++n)
                acc[m][n] = __builtin_amdgcn_mfma_f32_16x16x32_bf16(
                    af[m], bfr[n], acc[m][n], 0, 0, 0);
        __syncthreads();
    }

    // epilogue: C/D layout col=lane&15, row=(lane>>4)*4+r  [m89-verified]
#pragma unroll
    for (int m = 0; m < 4; ++m) {
#pragma unroll
        for (int n = 0; n < 4; ++n) {
            int col = bn + wc * 64 + n * 16 + fr;
            if (NGUARD && col >= N) continue;
            float bv = bias[col];
#pragma unroll
            for (int r = 0; r < 4; ++r) {
                int row = bm + wr * 64 + m * 16 + fq * 4 + r;
                float v = acc[m][n][r] + bv;
                if (OUT_BF16)
                    ((ushort*)Cp)[(size_t)row * ldc + col] = f2bf(v);
                else
                    ((float*)Cp)[(size_t)row * ldc + col] = v;
            }
        }
    }
}

// ---------------------------------------------------------------------------
// Softmax over K=7 taps; one thread per (m, h) row. In-place safe.
// ---------------------------------------------------------------------------
__global__ void softmax7(const float* __restrict__ q, float* __restrict__ w,
                         int rows) {
    int r = blockIdx.x * blockDim.x + threadIdx.x;
    if (r >= rows) return;
    const float* p = q + (size_t)r * K_TAPS;
    float mx = p[0];
#pragma unroll
    for (int k = 1; k < K_TAPS; ++k) mx = fmaxf(mx, p[k]);
    float e[K_TAPS], s = 0.f;
#pragma unroll
    for (int k = 0; k < K_TAPS; ++k) { e[k] = expf(p[k] - mx); s += e[k]; }
    float inv = 1.f / s;
    float* o = w + (size_t)r * K_TAPS;
#pragma unroll
    for (int k = 0; k < K_TAPS; ++k) o[k] = e[k] * inv;
}

// ---------------------------------------------------------------------------
// Dynamic conv (bf16 h in, bf16 conv out):
// out[m,c] = sum_k h[(t+k-3)*B+b, c] * w[m, c/64, k] + conv_bias[c]
// ---------------------------------------------------------------------------
__global__ __launch_bounds__(256) void dynconv_bf16(const ushort* __restrict__ h,
                                                    const float* __restrict__ w,
                                                    const float* __restrict__ cbias,
                                                    ushort* __restrict__ out) {
    const int m = blockIdx.x;
    const int t = m >> 4;
    const int b = m & 15;

    __shared__ float wsm[HK];
    if (threadIdx.x < HK)
        wsm[threadIdx.x] = w[(size_t)m * HK + threadIdx.x];
    __syncthreads();

    const int c = threadIdx.x * 4;
    const int hh = c >> 6;

    float4 bias = *(const float4*)&cbias[c];
    float a0 = bias.x, a1 = bias.y, a2 = bias.z, a3 = bias.w;

#pragma unroll
    for (int k = 0; k < K_TAPS; ++k) {
        int tt = t + k - PAD_LEFT;
        if (tt < 0 || tt >= T_DIM) continue;
        ushort4 hv = *(const ushort4*)&h[((size_t)tt * B_DIM + b) * C_DIM + c];
        float wk = wsm[hh * K_TAPS + k];
        a0 = fmaf(bf2f(hv.x), wk, a0);
        a1 = fmaf(bf2f(hv.y), wk, a1);
        a2 = fmaf(bf2f(hv.z), wk, a2);
        a3 = fmaf(bf2f(hv.w), wk, a3);
    }
    ushort4 o;
    o.x = f2bf(a0); o.y = f2bf(a1); o.z = f2bf(a2); o.w = f2bf(a3);
    *(ushort4*)&out[(size_t)m * C_DIM + c] = o;
}

// ---------------------------------------------------------------------------
extern "C" void kernel_launch(void* const* d_in, const int* in_sizes, int n_in,
                              void* d_out, int out_size, void* d_ws,
                              size_t ws_size, hipStream_t stream) {
    const float* x     = (const float*)d_in[0];
    const float* W1    = (const float*)d_in[1];
    const float* b1    = (const float*)d_in[2];
    const float* Wq    = (const float*)d_in[3];
    const float* bq    = (const float*)d_in[4];
    const float* cbias = (const float*)d_in[5];
    const float* W2    = (const float*)d_in[6];
    const float* b2    = (const float*)d_in[7];
    float* out = (float*)d_out;

    // workspace carve-up (all 16B aligned)
    ushort* xb    = (ushort*)d_ws;                         // 32 MB
    ushort* hb    = xb    + (size_t)M_DIM * C_DIM;         // 32 MB
    ushort* convb = hb    + (size_t)M_DIM * C_DIM;         // 32 MB
    ushort* W1t   = convb + (size_t)M_DIM * C_DIM;         // 2 MB
    ushort* W2t   = W1t   + (size_t)C_DIM * C_DIM;         // 2 MB
    ushort* Wqt   = W2t   + (size_t)C_DIM * OUT_DIM;       // 0.25 MB
    float*  q     = (float*)(Wqt + (size_t)HKP * C_DIM);   // 7.3 MB

    // 0) conversions / weight transposes
    cvt_bf16x8<<<dim3(M_DIM * C_DIM / 8 / 256), dim3(256), 0, stream>>>(
        x, xb, M_DIM * C_DIM / 8);
    transpose_cvt<<<dim3(C_DIM / 32, C_DIM / 32), dim3(32, 8), 0, stream>>>(
        W1, W1t, C_DIM, C_DIM, C_DIM);
    transpose_cvt<<<dim3(HKP / 32, C_DIM / 32), dim3(32, 8), 0, stream>>>(
        Wq, Wqt, C_DIM, HK, HKP);
    transpose_cvt<<<dim3(OUT_DIM / 32, C_DIM / 32), dim3(32, 8), 0, stream>>>(
        W2, W2t, C_DIM, OUT_DIM, OUT_DIM);

    // 1) h = bf16(x @ W1 + b1)
    gemm_mfma<true, false>
        <<<dim3(C_DIM / 128, M_DIM / 128), dim3(256), 0, stream>>>(
            xb, W1t, b1, hb, C_DIM, C_DIM, C_DIM);

    // 2) q = h @ Wq + bq   [16384 x 112], fp32 out
    gemm_mfma<false, true>
        <<<dim3(1, M_DIM / 128), dim3(256), 0, stream>>>(
            hb, Wqt, bq, q, C_DIM, HK, HK);

    // 3) softmax over taps
    softmax7<<<dim3((M_DIM * H_DIM + 255) / 256), dim3(256), 0, stream>>>(
        q, q, M_DIM * H_DIM);

    // 4) conv = bf16(dynconv(h, w) + conv_bias)
    dynconv_bf16<<<dim3(M_DIM), dim3(256), 0, stream>>>(hb, q, cbias, convb);

    // 5) out = conv @ W2 + b2  (fp32 out)
    gemm_mfma<false, false>
        <<<dim3(OUT_DIM / 128, M_DIM / 128), dim3(256), 0, stream>>>(
            convb, W2t, b2, out, C_DIM, OUT_DIM, OUT_DIM);
}